// Round 1
// baseline (254.361 us; speedup 1.0000x reference)
//
#include <hip/hip_runtime.h>

#define HH 4096
#define WW 4096
#define KK 256
#define RMAX 10

// Pass 1: scatter-add attractor contributions into addmap (= d_out reused).
__global__ void ecli_scatter(const int* __restrict__ pos,
                             const float* __restrict__ strength,
                             const float* __restrict__ local_ratio,
                             float* __restrict__ addmap) {
    const int k = blockIdx.x;
    const float s  = strength[k];
    const float lr = *local_ratio;
    const float radius = floorf(5.0f * s);          // <= 9 always (s < 2)
    const float inv    = -0.5f / (4.0f * s * s);
    const float amp    = lr * s;
    const int pi = pos[2 * k + 0];
    const int pj = pos[2 * k + 1];
    const int D = 2 * RMAX + 1;                      // 21
    for (int t = threadIdx.x; t < D * D; t += blockDim.x) {
        const int di = t / D - RMAX;
        const int dj = t % D - RMAX;
        if (fabsf((float)di) > radius || fabsf((float)dj) > radius) continue;
        const int ni = pi + di;
        const int nj = pj + dj;
        if (ni < 0 || ni >= HH || nj < 0 || nj >= WW) continue;
        const float dist2 = (float)(di * di + dj * dj);
        const float c = expf(dist2 * inv) * amp;
        atomicAdd(&addmap[(size_t)ni * WW + nj], c);
    }
}

// Pass 2: blend + accumulate squared norms (double) of field and field_update.
// addmap is read from `out` and `out` is overwritten with fu (same thread,
// same element -> no race).
__global__ void ecli_blend(const float* __restrict__ field,
                           const float* __restrict__ signal,
                           const float* __restrict__ gratio,
                           const float* __restrict__ infl,
                           float* __restrict__ out,
                           double* __restrict__ norms) {
    const int N4 = (HH * WW) / 4;
    const float gr = *gratio;
    const float is = *infl;
    double sf = 0.0;   // sum field^2
    double su = 0.0;   // sum fu^2
    const int stride = gridDim.x * blockDim.x;
    for (int idx = blockIdx.x * blockDim.x + threadIdx.x; idx < N4; idx += stride) {
        const float4 a = ((const float4*)out)[idx];
        const float4 f = ((const float4*)field)[idx];
        const float4 g = ((const float4*)signal)[idx];
        float4 r;
        {
            float m = is / (1.0f + expf(-(gr + a.x)));
            r.x = f.x * (1.0f - m) + g.x * m;
            sf += (double)f.x * (double)f.x; su += (double)r.x * (double)r.x;
        }
        {
            float m = is / (1.0f + expf(-(gr + a.y)));
            r.y = f.y * (1.0f - m) + g.y * m;
            sf += (double)f.y * (double)f.y; su += (double)r.y * (double)r.y;
        }
        {
            float m = is / (1.0f + expf(-(gr + a.z)));
            r.z = f.z * (1.0f - m) + g.z * m;
            sf += (double)f.z * (double)f.z; su += (double)r.z * (double)r.z;
        }
        {
            float m = is / (1.0f + expf(-(gr + a.w)));
            r.w = f.w * (1.0f - m) + g.w * m;
            sf += (double)f.w * (double)f.w; su += (double)r.w * (double)r.w;
        }
        ((float4*)out)[idx] = r;
    }
    // wave-64 butterfly reduce, then one atomic per wave
    #pragma unroll
    for (int off = 32; off > 0; off >>= 1) {
        sf += __shfl_down(sf, off);
        su += __shfl_down(su, off);
    }
    if ((threadIdx.x & 63) == 0) {
        atomicAdd(&norms[0], sf);
        atomicAdd(&norms[1], su);
    }
}

// Pass 3: out *= ||field|| / ||fu||  (1.0 if ||fu|| == 0)
__global__ void ecli_scale(float* __restrict__ out,
                           const double* __restrict__ norms) {
    const double nf = norms[0];
    const double nu = norms[1];
    const float scale = (nu > 0.0) ? (float)(sqrt(nf) / sqrt(nu)) : 1.0f;
    const int N4 = (HH * WW) / 4;
    const int stride = gridDim.x * blockDim.x;
    for (int idx = blockIdx.x * blockDim.x + threadIdx.x; idx < N4; idx += stride) {
        float4 v = ((const float4*)out)[idx];
        v.x *= scale; v.y *= scale; v.z *= scale; v.w *= scale;
        ((float4*)out)[idx] = v;
    }
}

extern "C" void kernel_launch(void* const* d_in, const int* in_sizes, int n_in,
                              void* d_out, int out_size, void* d_ws, size_t ws_size,
                              hipStream_t stream) {
    const float* field    = (const float*)d_in[0];
    const float* signal   = (const float*)d_in[1];
    const int*   pos      = (const int*)d_in[2];
    const float* strength = (const float*)d_in[3];
    const float* infl     = (const float*)d_in[4];
    const float* gratio   = (const float*)d_in[5];
    const float* lratio   = (const float*)d_in[6];
    float*  out   = (float*)d_out;
    double* norms = (double*)d_ws;

    // zero the accumulation map (d_out doubles as addmap) and the norm slots
    hipMemsetAsync(out, 0, (size_t)HH * WW * sizeof(float), stream);
    hipMemsetAsync(d_ws, 0, 2 * sizeof(double), stream);

    ecli_scatter<<<KK, 256, 0, stream>>>(pos, strength, lratio, out);
    ecli_blend<<<2048, 256, 0, stream>>>(field, signal, gratio, infl, out, norms);
    ecli_scale<<<2048, 256, 0, stream>>>(out, norms);
}